// Round 2
// baseline (573.491 us; speedup 1.0000x reference)
//
#include <hip/hip_runtime.h>

typedef unsigned short u16;
typedef unsigned int u32;

using short8 = __attribute__((ext_vector_type(8))) short;
using f32x4  = __attribute__((ext_vector_type(4))) float;
using f32x2  = __attribute__((ext_vector_type(2))) float;

#define SSEQ 512
#define BB   16
#define DD   256
#define G4   256      // 4*SS
#define SSZ  64       // SS
#define VV   10000
#define VPAD 10112    // 79*128
#define MALL 8192     // BB*SSEQ

// ---- ws layout (bytes) ----
#define OFF_XHI   0u
#define OFF_XLO   4194304u
#define OFF_WHI   8388608u
#define OFF_WLO   8519680u
#define OFF_WSY   8650752u
#define OFF_XPROJ 9945088u
#define OFF_HS    18333696u

__device__ __forceinline__ u16 f2bf(float f) {
  u32 u = __float_as_uint(f);
  u32 r = (u + 0x7fffu + ((u >> 16) & 1u)) >> 16;
  return (u16)r;
}
__device__ __forceinline__ float bf2f(u16 h) {
  return __uint_as_float(((u32)h) << 16);
}
__device__ __forceinline__ float sigm(float x) {
  float e = exp2f(-1.442695041f * x);
  return __builtin_amdgcn_rcpf(1.f + e);
}
__device__ __forceinline__ float tanh_fast(float x) {
  float xc = fminf(fmaxf(x, -20.f), 20.f);
  float z = exp2f(2.885390082f * xc);
  return (z - 1.f) * __builtin_amdgcn_rcpf(z + 1.f);
}
// packed dual-FMA (CDNA full-rate packed f32): c += a*b elementwise
__device__ __forceinline__ f32x2 pkfma(f32x2 a, f32x2 b, f32x2 c) {
  asm("v_pk_fma_f32 %0, %1, %2, %0" : "+v"(c) : "v"(a), "v"(b));
  return c;
}

// ---------------- K0: fp32 -> bf16 (hi/lo split for x, Wxs; padded bf16 Wsy) ----
#define NX 2097152
#define NW 65536
#define NP 647168   // VPAD*64
__global__ void k0_convert(const float* __restrict__ x, const float* __restrict__ Wxs,
                           const float* __restrict__ Wsy,
                           u16* __restrict__ xhi, u16* __restrict__ xlo,
                           u16* __restrict__ whi, u16* __restrict__ wlo,
                           u16* __restrict__ wsyb) {
  int i = blockIdx.x * 256 + threadIdx.x;
  if (i < NX) {
    float v = x[i]; u16 h = f2bf(v);
    xhi[i] = h; xlo[i] = f2bf(v - bf2f(h));
  } else if (i < NX + NW) {
    int j = i - NX;
    float v = Wxs[j]; u16 h = f2bf(v);
    whi[j] = h; wlo[j] = f2bf(v - bf2f(h));
  } else if (i < NX + NW + NP) {
    int j = i - NX - NW;
    wsyb[j] = (j < VV * SSZ) ? f2bf(Wsy[j]) : (u16)0;
  }
}

// ---------------- K1: xproj = x @ Wxs^T + b   (double-bf16 MFMA, fp32 out) ------
// M=8192, N=256, K=256. Tile 128x128, 4 waves (2x2), grid 64*2.
__global__ __launch_bounds__(256) void k1_xproj(
    const u16* __restrict__ xhi, const u16* __restrict__ xlo,
    const u16* __restrict__ whi, const u16* __restrict__ wlo,
    const float* __restrict__ bias, float* __restrict__ xproj) {
  int bid = blockIdx.x;
  int mb = bid >> 1, nb = bid & 1;
  int tid = threadIdx.x, l = tid & 63, wid = tid >> 6;
  int wm = wid >> 1, wv = wid & 1;
  int m0 = mb * 128 + wm * 64, n0 = nb * 128 + wv * 64;
  int lr = l & 15, lg = l >> 4;

  f32x4 acc[4][4];
#pragma unroll
  for (int a = 0; a < 4; a++)
#pragma unroll
    for (int bq = 0; bq < 4; bq++) acc[a][bq] = (f32x4){0.f, 0.f, 0.f, 0.f};

#pragma unroll
  for (int p = 0; p < 3; p++) {
    const u16* A = (p == 1) ? xlo : xhi;
    const u16* B = (p == 2) ? wlo : whi;
#pragma unroll
    for (int ks = 0; ks < 8; ks++) {
      short8 af[4], bf_[4];
#pragma unroll
      for (int fm = 0; fm < 4; fm++)
        af[fm] = *(const short8*)(A + (size_t)(m0 + fm * 16 + lr) * 256 + ks * 32 + lg * 8);
#pragma unroll
      for (int fv = 0; fv < 4; fv++)
        bf_[fv] = *(const short8*)(B + (size_t)(n0 + fv * 16 + lr) * 256 + ks * 32 + lg * 8);
#pragma unroll
      for (int fm = 0; fm < 4; fm++)
#pragma unroll
        for (int fv = 0; fv < 4; fv++)
          acc[fm][fv] = __builtin_amdgcn_mfma_f32_16x16x32_bf16(af[fm], bf_[fv], acc[fm][fv], 0, 0, 0);
    }
  }
#pragma unroll
  for (int fv = 0; fv < 4; fv++) {
    int j = n0 + fv * 16 + lr;
    float bj = bias[j];
#pragma unroll
    for (int fm = 0; fm < 4; fm++)
#pragma unroll
      for (int r = 0; r < 4; r++) {
        int m = m0 + fm * 16 + lg * 4 + r;
        xproj[(size_t)m * 256 + j] = acc[fm][fv][r] + bj;
      }
  }
}

// ---------------- K2: serial LSTM scan. 16 blocks (one per batch) x 1 wave -----
// Lane j owns output j: all 4 gate dot-products lane-local (Wss rows j,64+j,
// 128+j,192+j pinned in 256 VGPRs as f32x2 for v_pk_fma_f32). h broadcast via
// wave-private LDS roundtrip — NO barriers, NO cross-wave traffic.
__global__ __launch_bounds__(64, 1) void k2_scan(
    const float* __restrict__ xproj, const float* __restrict__ Wss,
    const float* __restrict__ Wssb, u16* __restrict__ hsb) {
  __shared__ float hbuf[64];
  int b = blockIdx.x, j = threadIdx.x;

  f32x2 wf[32], wi[32], wg[32], wo[32];
  {
    const f32x2* pf = (const f32x2*)(Wss + (size_t)j * 64);
    const f32x2* pi = (const f32x2*)(Wss + (size_t)(64 + j) * 64);
    const f32x2* pg = (const f32x2*)(Wss + (size_t)(128 + j) * 64);
    const f32x2* po = (const f32x2*)(Wss + (size_t)(192 + j) * 64);
#pragma unroll
    for (int q = 0; q < 32; q++) {
      wf[q] = pf[q]; wi[q] = pi[q]; wg[q] = pg[q]; wo[q] = po[q];
    }
  }
  float bf_ = Wssb[j], bi_ = Wssb[64 + j], bg_ = Wssb[128 + j], bo_ = Wssb[192 + j];

  f32x4 h4[16];
#pragma unroll
  for (int q = 0; q < 16; q++) h4[q] = (f32x4){0.f, 0.f, 0.f, 0.f};
  float c = 0.f;

  const float* xpb = xproj + (size_t)b * SSEQ * 256;
  u16* hout = hsb + (size_t)b * SSEQ * 64 + j;

  float xf = xpb[j], xi = xpb[64 + j], xg = xpb[128 + j], xo = xpb[192 + j];

  for (int t = 0; t < SSEQ; t++) {
    // prefetch next step's xproj (recurrence-independent addresses)
    float nf = 0.f, ni = 0.f, ng = 0.f, no_ = 0.f;
    if (t + 1 < SSEQ) {
      const float* xn = xpb + (size_t)(t + 1) * 256;
      nf = xn[j]; ni = xn[64 + j]; ng = xn[128 + j]; no_ = xn[192 + j];
    }

    f32x2 af = (f32x2){bf_ + xf, 0.f};
    f32x2 ai = (f32x2){bi_ + xi, 0.f};
    f32x2 ag = (f32x2){bg_ + xg, 0.f};
    f32x2 ao = (f32x2){bo_ + xo, 0.f};
#pragma unroll
    for (int q = 0; q < 16; q++) {
      f32x2 hA = (f32x2){h4[q][0], h4[q][1]};
      f32x2 hB = (f32x2){h4[q][2], h4[q][3]};
      af = pkfma(hA, wf[2 * q], af);     af = pkfma(hB, wf[2 * q + 1], af);
      ai = pkfma(hA, wi[2 * q], ai);     ai = pkfma(hB, wi[2 * q + 1], ai);
      ag = pkfma(hA, wg[2 * q], ag);     ag = pkfma(hB, wg[2 * q + 1], ag);
      ao = pkfma(hA, wo[2 * q], ao);     ao = pkfma(hB, wo[2 * q + 1], ao);
    }
    float vf = af[0] + af[1];
    float vi = ai[0] + ai[1];
    float vg = ag[0] + ag[1];
    float vo = ao[0] + ao[1];

    float fg = sigm(vf), ig = sigm(vi), og = sigm(vo);
    float gg = tanh_fast(vg);
    c = fmaf(c, fg, ig * gg);
    float hn = og * c;   // faithful to reference: no tanh(c)

    hout[(size_t)t * 64] = f2bf(hn);

    // wave-private broadcast: write own h, read all 64 (no barrier needed,
    // single wave; asm orders the compiler, lgkmcnt orders the DS unit)
    hbuf[j] = hn;
    asm volatile("s_waitcnt lgkmcnt(0)" ::: "memory");
    const f32x4* hb4 = (const f32x4*)hbuf;
#pragma unroll
    for (int q = 0; q < 16; q++) h4[q] = hb4[q];

    xf = nf; xi = ni; xg = ng; xo = no_;
  }
}

// ---------------- K3: y = hs @ Wsy^T + b   (bf16 MFMA, no LDS, fp32 out) -------
// M=8192, N=10000(pad 10112), K=64. Tile 128x128, grid 64*79.
__global__ __launch_bounds__(256) void k3_y(
    const u16* __restrict__ hsb, const u16* __restrict__ wsyb,
    const float* __restrict__ bias, float* __restrict__ y) {
  int bid = blockIdx.x;
  int mb = bid / 79, vb = bid - mb * 79;
  int tid = threadIdx.x, l = tid & 63, wid = tid >> 6;
  int wm = wid >> 1, wv = wid & 1;
  int m0 = mb * 128 + wm * 64, v0 = vb * 128 + wv * 64;
  int lr = l & 15, lg = l >> 4;

  f32x4 acc[4][4];
#pragma unroll
  for (int a = 0; a < 4; a++)
#pragma unroll
    for (int bq = 0; bq < 4; bq++) acc[a][bq] = (f32x4){0.f, 0.f, 0.f, 0.f};

#pragma unroll
  for (int ks = 0; ks < 2; ks++) {
    short8 af[4], bf_[4];
#pragma unroll
    for (int fm = 0; fm < 4; fm++)
      af[fm] = *(const short8*)(hsb + (size_t)(m0 + fm * 16 + lr) * 64 + ks * 32 + lg * 8);
#pragma unroll
    for (int fv = 0; fv < 4; fv++)
      bf_[fv] = *(const short8*)(wsyb + (size_t)(v0 + fv * 16 + lr) * 64 + ks * 32 + lg * 8);
#pragma unroll
    for (int fm = 0; fm < 4; fm++)
#pragma unroll
      for (int fv = 0; fv < 4; fv++)
        acc[fm][fv] = __builtin_amdgcn_mfma_f32_16x16x32_bf16(af[fm], bf_[fv], acc[fm][fv], 0, 0, 0);
  }

#pragma unroll
  for (int fv = 0; fv < 4; fv++) {
    int v = v0 + fv * 16 + lr;
    bool ok = (v < VV);
    float bv = ok ? bias[v] : 0.f;
#pragma unroll
    for (int fm = 0; fm < 4; fm++)
#pragma unroll
      for (int r = 0; r < 4; r++) {
        int m = m0 + fm * 16 + lg * 4 + r;
        if (ok) y[(size_t)m * (size_t)VV + v] = acc[fm][fv][r] + bv;
      }
  }
}

extern "C" void kernel_launch(void* const* d_in, const int* in_sizes, int n_in,
                              void* d_out, int out_size, void* d_ws, size_t ws_size,
                              hipStream_t stream) {
  const float* x     = (const float*)d_in[0];
  const float* Wxs_w = (const float*)d_in[1];
  const float* Wxs_b = (const float*)d_in[2];
  const float* Wss_w = (const float*)d_in[3];
  const float* Wss_b = (const float*)d_in[4];
  const float* Wsy_w = (const float*)d_in[5];
  const float* Wsy_b = (const float*)d_in[6];
  float* y = (float*)d_out;
  char* ws = (char*)d_ws;

  u16*   xhi   = (u16*)(ws + OFF_XHI);
  u16*   xlo   = (u16*)(ws + OFF_XLO);
  u16*   whi   = (u16*)(ws + OFF_WHI);
  u16*   wlo   = (u16*)(ws + OFF_WLO);
  u16*   wsyb  = (u16*)(ws + OFF_WSY);
  float* xproj = (float*)(ws + OFF_XPROJ);
  u16*   hsb   = (u16*)(ws + OFF_HS);

  k0_convert<<<(NX + NW + NP) / 256, 256, 0, stream>>>(x, Wxs_w, Wsy_w, xhi, xlo, whi, wlo, wsyb);
  k1_xproj<<<128, 256, 0, stream>>>(xhi, xlo, whi, wlo, Wxs_b, xproj);
  k2_scan<<<16, 64, 0, stream>>>(xproj, Wss_w, Wss_b, hsb);
  k3_y<<<64 * 79, 256, 0, stream>>>(hsb, wsyb, Wsy_b, y);
}

// Round 3
// 331.770 us; speedup vs baseline: 1.7286x; 1.7286x over previous
//
#include <hip/hip_runtime.h>

typedef unsigned short u16;
typedef unsigned int u32;

using short8 = __attribute__((ext_vector_type(8))) short;
using f32x4  = __attribute__((ext_vector_type(4))) float;
using f32x2  = __attribute__((ext_vector_type(2))) float;

#define SSEQ 512
#define BB   16
#define DD   256
#define G4   256      // 4*SS
#define SSZ  64       // SS
#define VV   10000
#define VPAD 10112    // 79*128
#define MALL 8192     // BB*SSEQ

// ---- ws layout (bytes) ----
#define OFF_XHI   0u
#define OFF_XLO   4194304u
#define OFF_WHI   8388608u
#define OFF_WLO   8519680u
#define OFF_WSY   8650752u
#define OFF_XPROJ 9945088u
#define OFF_HS    18333696u

__device__ __forceinline__ u16 f2bf(float f) {
  u32 u = __float_as_uint(f);
  u32 r = (u + 0x7fffu + ((u >> 16) & 1u)) >> 16;
  return (u16)r;
}
__device__ __forceinline__ float bf2f(u16 h) {
  return __uint_as_float(((u32)h) << 16);
}
__device__ __forceinline__ float sigm(float x) {
  float e = exp2f(-1.442695041f * x);
  return __builtin_amdgcn_rcpf(1.f + e);
}
__device__ __forceinline__ float tanh_fast(float x) {
  float xc = fminf(fmaxf(x, -20.f), 20.f);
  float z = exp2f(2.885390082f * xc);
  return (z - 1.f) * __builtin_amdgcn_rcpf(z + 1.f);
}
// packed dual-FMA (CDNA full-rate packed f32): c += a*b elementwise
__device__ __forceinline__ f32x2 pkfma(f32x2 a, f32x2 b, f32x2 c) {
  asm("v_pk_fma_f32 %0, %1, %2, %0" : "+v"(c) : "v"(a), "v"(b));
  return c;
}

// ---------------- K0: fp32 -> bf16 (hi/lo split for x, Wxs; padded bf16 Wsy) ----
#define NX 2097152
#define NW 65536
#define NP 647168   // VPAD*64
__global__ void k0_convert(const float* __restrict__ x, const float* __restrict__ Wxs,
                           const float* __restrict__ Wsy,
                           u16* __restrict__ xhi, u16* __restrict__ xlo,
                           u16* __restrict__ whi, u16* __restrict__ wlo,
                           u16* __restrict__ wsyb) {
  int i = blockIdx.x * 256 + threadIdx.x;
  if (i < NX) {
    float v = x[i]; u16 h = f2bf(v);
    xhi[i] = h; xlo[i] = f2bf(v - bf2f(h));
  } else if (i < NX + NW) {
    int j = i - NX;
    float v = Wxs[j]; u16 h = f2bf(v);
    whi[j] = h; wlo[j] = f2bf(v - bf2f(h));
  } else if (i < NX + NW + NP) {
    int j = i - NX - NW;
    wsyb[j] = (j < VV * SSZ) ? f2bf(Wsy[j]) : (u16)0;
  }
}

// ---------------- K1: xproj = x @ Wxs^T + b   (double-bf16 MFMA, fp32 out) ------
// M=8192, N=256, K=256. Tile 128x128, 4 waves (2x2), grid 64*2.
__global__ __launch_bounds__(256) void k1_xproj(
    const u16* __restrict__ xhi, const u16* __restrict__ xlo,
    const u16* __restrict__ whi, const u16* __restrict__ wlo,
    const float* __restrict__ bias, float* __restrict__ xproj) {
  int bid = blockIdx.x;
  int mb = bid >> 1, nb = bid & 1;
  int tid = threadIdx.x, l = tid & 63, wid = tid >> 6;
  int wm = wid >> 1, wv = wid & 1;
  int m0 = mb * 128 + wm * 64, n0 = nb * 128 + wv * 64;
  int lr = l & 15, lg = l >> 4;

  f32x4 acc[4][4];
#pragma unroll
  for (int a = 0; a < 4; a++)
#pragma unroll
    for (int bq = 0; bq < 4; bq++) acc[a][bq] = (f32x4){0.f, 0.f, 0.f, 0.f};

#pragma unroll
  for (int p = 0; p < 3; p++) {
    const u16* A = (p == 1) ? xlo : xhi;
    const u16* B = (p == 2) ? wlo : whi;
#pragma unroll
    for (int ks = 0; ks < 8; ks++) {
      short8 af[4], bf_[4];
#pragma unroll
      for (int fm = 0; fm < 4; fm++)
        af[fm] = *(const short8*)(A + (size_t)(m0 + fm * 16 + lr) * 256 + ks * 32 + lg * 8);
#pragma unroll
      for (int fv = 0; fv < 4; fv++)
        bf_[fv] = *(const short8*)(B + (size_t)(n0 + fv * 16 + lr) * 256 + ks * 32 + lg * 8);
#pragma unroll
      for (int fm = 0; fm < 4; fm++)
#pragma unroll
        for (int fv = 0; fv < 4; fv++)
          acc[fm][fv] = __builtin_amdgcn_mfma_f32_16x16x32_bf16(af[fm], bf_[fv], acc[fm][fv], 0, 0, 0);
    }
  }
#pragma unroll
  for (int fv = 0; fv < 4; fv++) {
    int j = n0 + fv * 16 + lr;
    float bj = bias[j];
#pragma unroll
    for (int fm = 0; fm < 4; fm++)
#pragma unroll
      for (int r = 0; r < 4; r++) {
        int m = m0 + fm * 16 + lg * 4 + r;
        xproj[(size_t)m * 256 + j] = acc[fm][fv][r] + bj;
      }
  }
}

// ---------------- K2: serial LSTM scan. 16 blocks x 4 waves, split-gate --------
// Wave w computes gate w for all 64 states (lane j: Wss row w*64+j in 64 VGPRs).
// Per step: 32 pkfma -> 1 nonlinearity/lane -> LDS gate exchange -> replicated
// c/h update -> LDS h broadcast (16 uniform ds_read_b128). Barriers are raw
// lgkmcnt(0)+s_barrier (no vmcnt drain). h history staged in LDS (64KB),
// dumped coalesced after the loop (no global stores inside the scan).
__global__ __launch_bounds__(256, 1) void k2_scan(
    const float* __restrict__ xproj, const float* __restrict__ Wss,
    const float* __restrict__ Wssb, u16* __restrict__ hsb) {
  __shared__ float gact[4][64];
  __shared__ float hbuf[64];
  __shared__ u16 hstage[SSEQ][64];   // 64 KB

  int b = blockIdx.x, tid = threadIdx.x;
  int w = tid >> 6, j = tid & 63;

  // weights: Wss row (w*64+j), 64 floats = 32 f32x2 VGPRs
  f32x2 wr[32];
  const f32x2* pw = (const f32x2*)(Wss + (size_t)(w * 64 + j) * 64);
#pragma unroll
  for (int q = 0; q < 32; q++) wr[q] = pw[q];
  float bg = Wssb[w * 64 + j];

  f32x4 h4[16];
#pragma unroll
  for (int q = 0; q < 16; q++) h4[q] = (f32x4){0.f, 0.f, 0.f, 0.f};
  float c = 0.f;   // replicated per wave (identical arithmetic)

  const float* xpb = xproj + (size_t)b * SSEQ * 256 + w * 64 + j;
  float xp0 = xpb[0];
  float xp1 = xpb[256];

  for (int t = 0; t < SSEQ; t++) {
    float xp2 = (t + 2 < SSEQ) ? xpb[(size_t)(t + 2) * 256] : 0.f;

    // dot(h, Wss_row) with 4 independent accumulators
    f32x2 a0 = (f32x2){bg + xp0, 0.f};
    f32x2 a1 = (f32x2){0.f, 0.f};
    f32x2 a2 = (f32x2){0.f, 0.f};
    f32x2 a3 = (f32x2){0.f, 0.f};
#pragma unroll
    for (int q = 0; q < 8; q++) {
      f32x2 hA0 = (f32x2){h4[2 * q][0], h4[2 * q][1]};
      f32x2 hB0 = (f32x2){h4[2 * q][2], h4[2 * q][3]};
      f32x2 hA1 = (f32x2){h4[2 * q + 1][0], h4[2 * q + 1][1]};
      f32x2 hB1 = (f32x2){h4[2 * q + 1][2], h4[2 * q + 1][3]};
      a0 = pkfma(hA0, wr[4 * q + 0], a0);
      a1 = pkfma(hB0, wr[4 * q + 1], a1);
      a2 = pkfma(hA1, wr[4 * q + 2], a2);
      a3 = pkfma(hB1, wr[4 * q + 3], a3);
    }
    float a = (a0[0] + a0[1]) + (a1[0] + a1[1]) + ((a2[0] + a2[1]) + (a3[0] + a3[1]));

    float act = (w == 2) ? tanh_fast(a) : sigm(a);   // wave-uniform branch
    gact[w][j] = act;
    asm volatile("s_waitcnt lgkmcnt(0)\n\ts_barrier" ::: "memory");

    float fg = gact[0][j], ig = gact[1][j], gg = gact[2][j], og = gact[3][j];
    c = fmaf(c, fg, ig * gg);
    float hn = og * c;     // faithful to reference: no tanh(c)

    if (w == 0) {
      hbuf[j] = hn;
      hstage[t][j] = f2bf(hn);
    }
    asm volatile("s_waitcnt lgkmcnt(0)\n\ts_barrier" ::: "memory");

    const f32x4* hb = (const f32x4*)hbuf;
#pragma unroll
    for (int q = 0; q < 16; q++) h4[q] = hb[q];   // wave-uniform broadcast reads

    xp0 = xp1; xp1 = xp2;
  }

  // coalesced dump of staged h history (64 KB) to global
  __syncthreads();
  const uint4* src = (const uint4*)hstage;
  uint4* dst = (uint4*)(hsb + (size_t)b * SSEQ * 64);
#pragma unroll
  for (int i = 0; i < 16; i++) dst[tid + 256 * i] = src[tid + 256 * i];
}

// ---------------- K3: y = hs @ Wsy^T + b   (bf16 MFMA, swapped operands) -------
// M=8192, N=10000(pad 10112), K=64. mfma(wsy_frag, hs_frag): acc col=m, row=v
// -> each lane's 4 acc regs = 4 consecutive v -> float4 stores.
__global__ __launch_bounds__(256) void k3_y(
    const u16* __restrict__ hsb, const u16* __restrict__ wsyb,
    const float* __restrict__ bias, float* __restrict__ y) {
  int bid = blockIdx.x;
  int mb = bid / 79, vb = bid - mb * 79;
  int tid = threadIdx.x, l = tid & 63, wid = tid >> 6;
  int wm = wid >> 1, wv = wid & 1;
  int m0 = mb * 128 + wm * 64, v0 = vb * 128 + wv * 64;
  int lr = l & 15, lg = l >> 4;

  f32x4 acc[4][4];  // [fv][fm]
#pragma unroll
  for (int a = 0; a < 4; a++)
#pragma unroll
    for (int bq = 0; bq < 4; bq++) acc[a][bq] = (f32x4){0.f, 0.f, 0.f, 0.f};

#pragma unroll
  for (int ks = 0; ks < 2; ks++) {
    short8 af[4], bf_[4];
#pragma unroll
    for (int fm = 0; fm < 4; fm++)
      af[fm] = *(const short8*)(hsb + (size_t)(m0 + fm * 16 + lr) * 64 + ks * 32 + lg * 8);
#pragma unroll
    for (int fv = 0; fv < 4; fv++)
      bf_[fv] = *(const short8*)(wsyb + (size_t)(v0 + fv * 16 + lr) * 64 + ks * 32 + lg * 8);
#pragma unroll
    for (int fv = 0; fv < 4; fv++)
#pragma unroll
      for (int fm = 0; fm < 4; fm++)
        acc[fv][fm] = __builtin_amdgcn_mfma_f32_16x16x32_bf16(bf_[fv], af[fm], acc[fv][fm], 0, 0, 0);
  }

#pragma unroll
  for (int fv = 0; fv < 4; fv++) {
    int vb4 = v0 + fv * 16 + lg * 4;      // 4 consecutive v per lane
    bool ok = (vb4 + 3) < VV;
    float4 bv = ok ? *(const float4*)(bias + vb4) : float4{0.f, 0.f, 0.f, 0.f};
#pragma unroll
    for (int fm = 0; fm < 4; fm++) {
      int m = m0 + fm * 16 + lr;
      if (ok) {
        float4 o;
        o.x = acc[fv][fm][0] + bv.x;
        o.y = acc[fv][fm][1] + bv.y;
        o.z = acc[fv][fm][2] + bv.z;
        o.w = acc[fv][fm][3] + bv.w;
        *(float4*)(y + (size_t)m * (size_t)VV + vb4) = o;
      }
    }
  }
}

extern "C" void kernel_launch(void* const* d_in, const int* in_sizes, int n_in,
                              void* d_out, int out_size, void* d_ws, size_t ws_size,
                              hipStream_t stream) {
  const float* x     = (const float*)d_in[0];
  const float* Wxs_w = (const float*)d_in[1];
  const float* Wxs_b = (const float*)d_in[2];
  const float* Wss_w = (const float*)d_in[3];
  const float* Wss_b = (const float*)d_in[4];
  const float* Wsy_w = (const float*)d_in[5];
  const float* Wsy_b = (const float*)d_in[6];
  float* y = (float*)d_out;
  char* ws = (char*)d_ws;

  u16*   xhi   = (u16*)(ws + OFF_XHI);
  u16*   xlo   = (u16*)(ws + OFF_XLO);
  u16*   whi   = (u16*)(ws + OFF_WHI);
  u16*   wlo   = (u16*)(ws + OFF_WLO);
  u16*   wsyb  = (u16*)(ws + OFF_WSY);
  float* xproj = (float*)(ws + OFF_XPROJ);
  u16*   hsb   = (u16*)(ws + OFF_HS);

  k0_convert<<<(NX + NW + NP) / 256, 256, 0, stream>>>(x, Wxs_w, Wsy_w, xhi, xlo, whi, wlo, wsyb);
  k1_xproj<<<128, 256, 0, stream>>>(xhi, xlo, whi, wlo, Wxs_b, xproj);
  k2_scan<<<16, 256, 0, stream>>>(xproj, Wss_w, Wss_b, hsb);
  k3_y<<<64 * 79, 256, 0, stream>>>(hsb, wsyb, Wsy_b, y);
}

// Round 4
// 328.374 us; speedup vs baseline: 1.7465x; 1.0103x over previous
//
#include <hip/hip_runtime.h>

typedef unsigned short u16;
typedef unsigned int u32;

using short8 = __attribute__((ext_vector_type(8))) short;
using f32x4  = __attribute__((ext_vector_type(4))) float;
using f32x2  = __attribute__((ext_vector_type(2))) float;

#define SSEQ 512
#define BB   16
#define DD   256
#define G4   256      // 4*SS
#define SSZ  64       // SS
#define VV   10000
#define VPAD 10112    // 79*128
#define MALL 8192     // BB*SSEQ

// ---- ws layout (bytes) ----
#define OFF_XHI   0u
#define OFF_XLO   4194304u
#define OFF_WHI   8388608u
#define OFF_WLO   8519680u
#define OFF_WSY   8650752u
#define OFF_XPROJ 9945088u
#define OFF_HS    18333696u

__device__ __forceinline__ u16 f2bf(float f) {
  u32 u = __float_as_uint(f);
  u32 r = (u + 0x7fffu + ((u >> 16) & 1u)) >> 16;
  return (u16)r;
}
__device__ __forceinline__ float bf2f(u16 h) {
  return __uint_as_float(((u32)h) << 16);
}
// packed dual-FMA: c += a*b elementwise (reg-compact; issue-rate same as scalar)
__device__ __forceinline__ f32x2 pkfma(f32x2 a, f32x2 b, f32x2 c) {
  asm("v_pk_fma_f32 %0, %1, %2, %0" : "+v"(c) : "v"(a), "v"(b));
  return c;
}

// ---------------- K0: fp32 -> bf16 (hi/lo split for x, Wxs; padded bf16 Wsy) ----
#define NX 2097152
#define NW 65536
#define NP 647168   // VPAD*64
__global__ void k0_convert(const float* __restrict__ x, const float* __restrict__ Wxs,
                           const float* __restrict__ Wsy,
                           u16* __restrict__ xhi, u16* __restrict__ xlo,
                           u16* __restrict__ whi, u16* __restrict__ wlo,
                           u16* __restrict__ wsyb) {
  int i = blockIdx.x * 256 + threadIdx.x;
  if (i < NX) {
    float v = x[i]; u16 h = f2bf(v);
    xhi[i] = h; xlo[i] = f2bf(v - bf2f(h));
  } else if (i < NX + NW) {
    int j = i - NX;
    float v = Wxs[j]; u16 h = f2bf(v);
    whi[j] = h; wlo[j] = f2bf(v - bf2f(h));
  } else if (i < NX + NW + NP) {
    int j = i - NX - NW;
    wsyb[j] = (j < VV * SSZ) ? f2bf(Wsy[j]) : (u16)0;
  }
}

// ---------------- K1: xproj = x @ Wxs^T + b   (double-bf16 MFMA, fp32 out) ------
// M=8192, N=256, K=256. Tile 128x128, 4 waves (2x2), grid 64*2.
__global__ __launch_bounds__(256) void k1_xproj(
    const u16* __restrict__ xhi, const u16* __restrict__ xlo,
    const u16* __restrict__ whi, const u16* __restrict__ wlo,
    const float* __restrict__ bias, float* __restrict__ xproj) {
  int bid = blockIdx.x;
  int mb = bid >> 1, nb = bid & 1;
  int tid = threadIdx.x, l = tid & 63, wid = tid >> 6;
  int wm = wid >> 1, wv = wid & 1;
  int m0 = mb * 128 + wm * 64, n0 = nb * 128 + wv * 64;
  int lr = l & 15, lg = l >> 4;

  f32x4 acc[4][4];
#pragma unroll
  for (int a = 0; a < 4; a++)
#pragma unroll
    for (int bq = 0; bq < 4; bq++) acc[a][bq] = (f32x4){0.f, 0.f, 0.f, 0.f};

#pragma unroll
  for (int p = 0; p < 3; p++) {
    const u16* A = (p == 1) ? xlo : xhi;
    const u16* B = (p == 2) ? wlo : whi;
#pragma unroll
    for (int ks = 0; ks < 8; ks++) {
      short8 af[4], bf_[4];
#pragma unroll
      for (int fm = 0; fm < 4; fm++)
        af[fm] = *(const short8*)(A + (size_t)(m0 + fm * 16 + lr) * 256 + ks * 32 + lg * 8);
#pragma unroll
      for (int fv = 0; fv < 4; fv++)
        bf_[fv] = *(const short8*)(B + (size_t)(n0 + fv * 16 + lr) * 256 + ks * 32 + lg * 8);
#pragma unroll
      for (int fm = 0; fm < 4; fm++)
#pragma unroll
        for (int fv = 0; fv < 4; fv++)
          acc[fm][fv] = __builtin_amdgcn_mfma_f32_16x16x32_bf16(af[fm], bf_[fv], acc[fm][fv], 0, 0, 0);
    }
  }
#pragma unroll
  for (int fv = 0; fv < 4; fv++) {
    int j = n0 + fv * 16 + lr;
    float bj = bias[j];
#pragma unroll
    for (int fm = 0; fm < 4; fm++)
#pragma unroll
      for (int r = 0; r < 4; r++) {
        int m = m0 + fm * 16 + lg * 4 + r;
        xproj[(size_t)m * 256 + j] = acc[fm][fv][r] + bj;
      }
  }
}

// ---------------- K2: serial LSTM scan. 16 blocks x 4 waves ---------------------
// Wave w owns states 16w..16w+15. Lane (g=l>>4, s=l&15) computes gate g of
// state jj=16w+s (Wss row g*64+jj in 64 VGPRs). Gate gather = 4 intra-wave
// shfl (no barrier). ONE barrier/step for the h broadcast (double-buffered).
// Activation branch removed: act = A + B*rcp(exp2(k*a)+1), per-lane (A,B,k).
__global__ __launch_bounds__(256, 1) void k2_scan(
    const float* __restrict__ xproj, const float* __restrict__ Wss,
    const float* __restrict__ Wssb, u16* __restrict__ hsb) {
  __shared__ float hbuf[2][64];
  __shared__ u16 hstage[SSEQ][64];   // 64 KB

  int b = blockIdx.x, tid = threadIdx.x;
  int w = tid >> 6, l = tid & 63;
  int s = l & 15, g = l >> 4;
  int jj = w * 16 + s;          // state this lane helps compute
  int row = g * 64 + jj;        // Wss row / gate index

  f32x2 wr[32];
  const f32x2* pw = (const f32x2*)(Wss + (size_t)row * 64);
#pragma unroll
  for (int q = 0; q < 32; q++) wr[q] = pw[q];
  float bg = Wssb[row];

  // unified activation constants: sigm -> k=-1/ln2 scale, A=0, B=1
  //                               tanh -> k=+2/ln2 scale, A=1, B=-2
  float kk = (g == 2) ? 2.885390082f : -1.442695041f;
  float Ac = (g == 2) ? 1.f : 0.f;
  float Bc = (g == 2) ? -2.f : 1.f;

  f32x4 h4[16];
#pragma unroll
  for (int q = 0; q < 16; q++) h4[q] = (f32x4){0.f, 0.f, 0.f, 0.f};
  float c = 0.f;   // replicated across the 4 gate-lanes of state jj

  const float* xpb = xproj + (size_t)b * SSEQ * 256 + row;
  float xp0 = xpb[0];
  float xp1 = xpb[256];

  for (int t = 0; t < SSEQ; t++) {
    float xp2 = (t + 2 < SSEQ) ? xpb[(size_t)(t + 2) * 256] : 0.f;

    // dot(h, Wss_row): 32 pkfma, 4 independent accumulators
    f32x2 a0 = (f32x2){bg + xp0, 0.f};
    f32x2 a1 = (f32x2){0.f, 0.f};
    f32x2 a2 = (f32x2){0.f, 0.f};
    f32x2 a3 = (f32x2){0.f, 0.f};
#pragma unroll
    for (int q = 0; q < 8; q++) {
      f32x2 hA0 = (f32x2){h4[2 * q][0], h4[2 * q][1]};
      f32x2 hB0 = (f32x2){h4[2 * q][2], h4[2 * q][3]};
      f32x2 hA1 = (f32x2){h4[2 * q + 1][0], h4[2 * q + 1][1]};
      f32x2 hB1 = (f32x2){h4[2 * q + 1][2], h4[2 * q + 1][3]};
      a0 = pkfma(hA0, wr[4 * q + 0], a0);
      a1 = pkfma(hB0, wr[4 * q + 1], a1);
      a2 = pkfma(hA1, wr[4 * q + 2], a2);
      a3 = pkfma(hB1, wr[4 * q + 3], a3);
    }
    float a = ((a0[0] + a0[1]) + (a1[0] + a1[1])) + ((a2[0] + a2[1]) + (a3[0] + a3[1]));

    float z = exp2f(kk * a);
    float act = fmaf(Bc, __builtin_amdgcn_rcpf(z + 1.f), Ac);

    // gather the 4 gates of state jj (same wave: lanes s,16+s,32+s,48+s)
    float fg = __shfl(act, s, 64);
    float ig = __shfl(act, 16 + s, 64);
    float gg = __shfl(act, 32 + s, 64);
    float og = __shfl(act, 48 + s, 64);

    c = fmaf(c, fg, ig * gg);
    float hn = og * c;     // faithful to reference: no tanh(c)

    if (g == 0) {
      hbuf[t & 1][jj] = hn;
      hstage[t][jj] = f2bf(hn);
    }
    // flush ds_write, then ONE barrier; no vmcnt drain (xp prefetch in flight)
    asm volatile("s_waitcnt lgkmcnt(0)\n\ts_barrier" ::: "memory");

    const f32x4* hb = (const f32x4*)hbuf[t & 1];
#pragma unroll
    for (int q = 0; q < 16; q++) h4[q] = hb[q];   // wave-uniform broadcast reads

    xp0 = xp1; xp1 = xp2;
  }

  // coalesced dump of staged h history (64 KB) to global
  __syncthreads();
  const uint4* src = (const uint4*)hstage;
  uint4* dst = (uint4*)(hsb + (size_t)b * SSEQ * 64);
#pragma unroll
  for (int i = 0; i < 16; i++) dst[tid + 256 * i] = src[tid + 256 * i];
}

// ---------------- K3: y = hs @ Wsy^T + b   (bf16 MFMA, swapped operands) -------
// M=8192, N=10000(pad 10112), K=64. mfma(wsy_frag, hs_frag): acc col=m, row=v
// -> each lane's 4 acc regs = 4 consecutive v -> float4 stores.
__global__ __launch_bounds__(256) void k3_y(
    const u16* __restrict__ hsb, const u16* __restrict__ wsyb,
    const float* __restrict__ bias, float* __restrict__ y) {
  int bid = blockIdx.x;
  int mb = bid / 79, vb = bid - mb * 79;
  int tid = threadIdx.x, l = tid & 63, wid = tid >> 6;
  int wm = wid >> 1, wv = wid & 1;
  int m0 = mb * 128 + wm * 64, v0 = vb * 128 + wv * 64;
  int lr = l & 15, lg = l >> 4;

  f32x4 acc[4][4];  // [fv][fm]
#pragma unroll
  for (int a = 0; a < 4; a++)
#pragma unroll
    for (int bq = 0; bq < 4; bq++) acc[a][bq] = (f32x4){0.f, 0.f, 0.f, 0.f};

#pragma unroll
  for (int ks = 0; ks < 2; ks++) {
    short8 af[4], bf_[4];
#pragma unroll
    for (int fm = 0; fm < 4; fm++)
      af[fm] = *(const short8*)(hsb + (size_t)(m0 + fm * 16 + lr) * 64 + ks * 32 + lg * 8);
#pragma unroll
    for (int fv = 0; fv < 4; fv++)
      bf_[fv] = *(const short8*)(wsyb + (size_t)(v0 + fv * 16 + lr) * 64 + ks * 32 + lg * 8);
#pragma unroll
    for (int fv = 0; fv < 4; fv++)
#pragma unroll
      for (int fm = 0; fm < 4; fm++)
        acc[fv][fm] = __builtin_amdgcn_mfma_f32_16x16x32_bf16(bf_[fv], af[fm], acc[fv][fm], 0, 0, 0);
  }

#pragma unroll
  for (int fv = 0; fv < 4; fv++) {
    int vb4 = v0 + fv * 16 + lg * 4;      // 4 consecutive v per lane
    bool ok = (vb4 + 3) < VV;
    float4 bv = ok ? *(const float4*)(bias + vb4) : float4{0.f, 0.f, 0.f, 0.f};
#pragma unroll
    for (int fm = 0; fm < 4; fm++) {
      int m = m0 + fm * 16 + lr;
      if (ok) {
        float4 o;
        o.x = acc[fv][fm][0] + bv.x;
        o.y = acc[fv][fm][1] + bv.y;
        o.z = acc[fv][fm][2] + bv.z;
        o.w = acc[fv][fm][3] + bv.w;
        *(float4*)(y + (size_t)m * (size_t)VV + vb4) = o;
      }
    }
  }
}

extern "C" void kernel_launch(void* const* d_in, const int* in_sizes, int n_in,
                              void* d_out, int out_size, void* d_ws, size_t ws_size,
                              hipStream_t stream) {
  const float* x     = (const float*)d_in[0];
  const float* Wxs_w = (const float*)d_in[1];
  const float* Wxs_b = (const float*)d_in[2];
  const float* Wss_w = (const float*)d_in[3];
  const float* Wss_b = (const float*)d_in[4];
  const float* Wsy_w = (const float*)d_in[5];
  const float* Wsy_b = (const float*)d_in[6];
  float* y = (float*)d_out;
  char* ws = (char*)d_ws;

  u16*   xhi   = (u16*)(ws + OFF_XHI);
  u16*   xlo   = (u16*)(ws + OFF_XLO);
  u16*   whi   = (u16*)(ws + OFF_WHI);
  u16*   wlo   = (u16*)(ws + OFF_WLO);
  u16*   wsyb  = (u16*)(ws + OFF_WSY);
  float* xproj = (float*)(ws + OFF_XPROJ);
  u16*   hsb   = (u16*)(ws + OFF_HS);

  k0_convert<<<(NX + NW + NP) / 256, 256, 0, stream>>>(x, Wxs_w, Wsy_w, xhi, xlo, whi, wlo, wsyb);
  k1_xproj<<<128, 256, 0, stream>>>(xhi, xlo, whi, wlo, Wxs_b, xproj);
  k2_scan<<<16, 256, 0, stream>>>(xproj, Wss_w, Wss_b, hsb);
  k3_y<<<64 * 79, 256, 0, stream>>>(hsb, wsyb, Wsy_b, y);
}

// Round 6
// 315.536 us; speedup vs baseline: 1.8175x; 1.0407x over previous
//
#include <hip/hip_runtime.h>

typedef unsigned short u16;
typedef unsigned int u32;

using short8 = __attribute__((ext_vector_type(8))) short;
using f32x4  = __attribute__((ext_vector_type(4))) float;
using f32x2  = __attribute__((ext_vector_type(2))) float;

#define SSEQ 512
#define BB   16
#define DD   256
#define G4   256      // 4*SS
#define SSZ  64       // SS
#define VV   10000
#define VPAD 10112    // 79*128
#define MALL 8192     // BB*SSEQ

// ---- ws layout (bytes) ----
#define OFF_XHI   0u
#define OFF_XLO   4194304u
#define OFF_WHI   8388608u
#define OFF_WLO   8519680u
#define OFF_WSY   8650752u
#define OFF_XPROJ 9945088u
#define OFF_HS    18333696u

__device__ __forceinline__ u16 f2bf(float f) {
  u32 u = __float_as_uint(f);
  u32 r = (u + 0x7fffu + ((u >> 16) & 1u)) >> 16;
  return (u16)r;
}
__device__ __forceinline__ float bf2f(u16 h) {
  return __uint_as_float(((u32)h) << 16);
}
// packed dual-FMA: c += a*b elementwise
__device__ __forceinline__ f32x2 pkfma(f32x2 a, f32x2 b, f32x2 c) {
  asm("v_pk_fma_f32 %0, %1, %2, %0" : "+v"(c) : "v"(a), "v"(b));
  return c;
}
// quad butterfly add via DPP (VALU pipe — keeps DS free)
// CTRL 0xB1 = quad_perm[1,0,3,2] (xor1), 0x4E = quad_perm[2,3,0,1] (xor2)
template <int CTRL>
__device__ __forceinline__ float qadd(float x) {
  int pv = __builtin_amdgcn_update_dpp(0, __float_as_int(x), CTRL, 0xf, 0xf, true);
  return x + __int_as_float(pv);
}

// ---------------- K0: fp32 -> bf16 (hi/lo split for x, Wxs; padded bf16 Wsy) ----
#define NX 2097152
#define NW 65536
#define NP 647168   // VPAD*64
__global__ void k0_convert(const float* __restrict__ x, const float* __restrict__ Wxs,
                           const float* __restrict__ Wsy,
                           u16* __restrict__ xhi, u16* __restrict__ xlo,
                           u16* __restrict__ whi, u16* __restrict__ wlo,
                           u16* __restrict__ wsyb) {
  int i = blockIdx.x * 256 + threadIdx.x;
  if (i < NX) {
    float v = x[i]; u16 h = f2bf(v);
    xhi[i] = h; xlo[i] = f2bf(v - bf2f(h));
  } else if (i < NX + NW) {
    int j = i - NX;
    float v = Wxs[j]; u16 h = f2bf(v);
    whi[j] = h; wlo[j] = f2bf(v - bf2f(h));
  } else if (i < NX + NW + NP) {
    int j = i - NX - NW;
    wsyb[j] = (j < VV * SSZ) ? f2bf(Wsy[j]) : (u16)0;
  }
}

// ---------------- K1: xproj = x @ Wxs^T + b   (double-bf16 MFMA, fp32 out) ------
__global__ __launch_bounds__(256) void k1_xproj(
    const u16* __restrict__ xhi, const u16* __restrict__ xlo,
    const u16* __restrict__ whi, const u16* __restrict__ wlo,
    const float* __restrict__ bias, float* __restrict__ xproj) {
  int bid = blockIdx.x;
  int mb = bid >> 1, nb = bid & 1;
  int tid = threadIdx.x, l = tid & 63, wid = tid >> 6;
  int wm = wid >> 1, wv = wid & 1;
  int m0 = mb * 128 + wm * 64, n0 = nb * 128 + wv * 64;
  int lr = l & 15, lg = l >> 4;

  f32x4 acc[4][4];
#pragma unroll
  for (int a = 0; a < 4; a++)
#pragma unroll
    for (int bq = 0; bq < 4; bq++) acc[a][bq] = (f32x4){0.f, 0.f, 0.f, 0.f};

#pragma unroll
  for (int p = 0; p < 3; p++) {
    const u16* A = (p == 1) ? xlo : xhi;
    const u16* B = (p == 2) ? wlo : whi;
#pragma unroll
    for (int ks = 0; ks < 8; ks++) {
      short8 af[4], bf_[4];
#pragma unroll
      for (int fm = 0; fm < 4; fm++)
        af[fm] = *(const short8*)(A + (size_t)(m0 + fm * 16 + lr) * 256 + ks * 32 + lg * 8);
#pragma unroll
      for (int fv = 0; fv < 4; fv++)
        bf_[fv] = *(const short8*)(B + (size_t)(n0 + fv * 16 + lr) * 256 + ks * 32 + lg * 8);
#pragma unroll
      for (int fm = 0; fm < 4; fm++)
#pragma unroll
        for (int fv = 0; fv < 4; fv++)
          acc[fm][fv] = __builtin_amdgcn_mfma_f32_16x16x32_bf16(af[fm], bf_[fv], acc[fm][fv], 0, 0, 0);
    }
  }
#pragma unroll
  for (int fv = 0; fv < 4; fv++) {
    int j = n0 + fv * 16 + lr;
    float bj = bias[j];
#pragma unroll
    for (int fm = 0; fm < 4; fm++)
#pragma unroll
      for (int r = 0; r < 4; r++) {
        int m = m0 + fm * 16 + lg * 4 + r;
        xproj[(size_t)m * 256 + j] = acc[fm][fv][r] + bj;
      }
  }
}

// ---------------- K2: serial LSTM scan. 16 blocks x 4 waves, k-split ----------
// Lane (w, oo=l>>2, ks=l&3): computes ALL 4 gates of state jj=16w+oo over
// k-slice [16ks,16ks+16). h-read = 4 ds_read_b128/lane (16/CU — was 64/CU).
// Quad butterfly (DPP, VALU pipe) completes the dot; act/c/h quad-redundant.
// ONE barrier/step; double-buffered hbuf; no vmcnt drain in loop.
__global__ __launch_bounds__(256, 1) void k2_scan(
    const float* __restrict__ xproj, const float* __restrict__ Wss,
    const float* __restrict__ Wssb, u16* __restrict__ hsb) {
  __shared__ float hbuf[2][64];
  __shared__ u16 hstage[SSEQ][64];   // 64 KB

  int b = blockIdx.x, tid = threadIdx.x;
  int w = tid >> 6, l = tid & 63;
  int oo = l >> 2, ks = l & 3;
  int jj = w * 16 + oo;          // state this quad computes

  // weights: 4 gate-rows of state jj, k-slice [16ks,16ks+16) -> 64 VGPRs
  f32x2 wr[32];
  float bias4[4];
#pragma unroll
  for (int g = 0; g < 4; g++) {
    const f32x2* pw = (const f32x2*)(Wss + (size_t)(g * 64 + jj) * 64 + ks * 16);
#pragma unroll
    for (int q = 0; q < 8; q++) wr[g * 8 + q] = pw[q];
    bias4[g] = Wssb[g * 64 + jj];
  }

  const float* xpb = xproj + (size_t)b * SSEQ * 256 + jj;
  float xpc[4], xpn[4];
#pragma unroll
  for (int g = 0; g < 4; g++) xpc[g] = xpb[g * 64];

  if (tid < 128) ((float*)hbuf)[tid] = 0.f;
  __syncthreads();

  float c = 0.f;   // state jj's cell, replicated across the quad

  for (int t = 0; t < SSEQ; t++) {
    int rb = (t + 1) & 1;        // read h_{t-1}
    f32x4 h4[4];
    const f32x4* hb = (const f32x4*)&hbuf[rb][ks * 16];
    h4[0] = hb[0]; h4[1] = hb[1]; h4[2] = hb[2]; h4[3] = hb[3];

    if (t + 1 < SSEQ) {
      const float* xn = xpb + (size_t)(t + 1) * 256;
#pragma unroll
      for (int g = 0; g < 4; g++) xpn[g] = xn[g * 64];
    }

    // 16-k partial dot for each of the 4 gates (32 pkfma total)
    float p[4];
#pragma unroll
    for (int g = 0; g < 4; g++) {
      f32x2 a0 = (f32x2){0.f, 0.f}, a1 = (f32x2){0.f, 0.f};
#pragma unroll
      for (int q = 0; q < 4; q++) {
        f32x2 hA = (f32x2){h4[q][0], h4[q][1]};
        f32x2 hB = (f32x2){h4[q][2], h4[q][3]};
        a0 = pkfma(hA, wr[g * 8 + 2 * q], a0);
        a1 = pkfma(hB, wr[g * 8 + 2 * q + 1], a1);
      }
      p[g] = (a0[0] + a0[1]) + (a1[0] + a1[1]);
    }

    // quad butterfly: sum the 4 k-slices (DPP, no DS traffic)
#pragma unroll
    for (int g = 0; g < 4; g++) p[g] = qadd<0x4E>(qadd<0xB1>(p[g]));

    float pf = p[0] + xpc[0] + bias4[0];
    float pi = p[1] + xpc[1] + bias4[1];
    float pg = p[2] + xpc[2] + bias4[2];
    float po = p[3] + xpc[3] + bias4[3];

    float fg = __builtin_amdgcn_rcpf(1.f + exp2f(-1.442695041f * pf));
    float ig = __builtin_amdgcn_rcpf(1.f + exp2f(-1.442695041f * pi));
    float og = __builtin_amdgcn_rcpf(1.f + exp2f(-1.442695041f * po));
    float gg = fmaf(-2.f, __builtin_amdgcn_rcpf(exp2f(2.885390082f * pg) + 1.f), 1.f);

    c = fmaf(c, fg, ig * gg);
    float hn = og * c;     // faithful to reference: no tanh(c)

    if (ks == 0) {
      hbuf[t & 1][jj] = hn;
      hstage[t][jj] = f2bf(hn);
    }
    asm volatile("s_waitcnt lgkmcnt(0)\n\ts_barrier" ::: "memory");

#pragma unroll
    for (int g = 0; g < 4; g++) xpc[g] = xpn[g];
  }

  // coalesced dump of staged h history (64 KB) to global
  __syncthreads();
  const uint4* src = (const uint4*)hstage;
  uint4* dst = (uint4*)(hsb + (size_t)b * SSEQ * 64);
#pragma unroll
  for (int i = 0; i < 16; i++) dst[tid + 256 * i] = src[tid + 256 * i];
}

// ---------------- K3: y = hs @ Wsy^T + b   (bf16 MFMA, swapped operands) -------
__global__ __launch_bounds__(256) void k3_y(
    const u16* __restrict__ hsb, const u16* __restrict__ wsyb,
    const float* __restrict__ bias, float* __restrict__ y) {
  int bid = blockIdx.x;
  int mb = bid / 79, vb = bid - mb * 79;
  int tid = threadIdx.x, l = tid & 63, wid = tid >> 6;
  int wm = wid >> 1, wv = wid & 1;
  int m0 = mb * 128 + wm * 64, v0 = vb * 128 + wv * 64;
  int lr = l & 15, lg = l >> 4;

  f32x4 acc[4][4];  // [fv][fm]
#pragma unroll
  for (int a = 0; a < 4; a++)
#pragma unroll
    for (int bq = 0; bq < 4; bq++) acc[a][bq] = (f32x4){0.f, 0.f, 0.f, 0.f};

#pragma unroll
  for (int ks = 0; ks < 2; ks++) {
    short8 af[4], bf_[4];
#pragma unroll
    for (int fm = 0; fm < 4; fm++)
      af[fm] = *(const short8*)(hsb + (size_t)(m0 + fm * 16 + lr) * 64 + ks * 32 + lg * 8);
#pragma unroll
    for (int fv = 0; fv < 4; fv++)
      bf_[fv] = *(const short8*)(wsyb + (size_t)(v0 + fv * 16 + lr) * 64 + ks * 32 + lg * 8);
#pragma unroll
    for (int fv = 0; fv < 4; fv++)
#pragma unroll
      for (int fm = 0; fm < 4; fm++)
        acc[fv][fm] = __builtin_amdgcn_mfma_f32_16x16x32_bf16(bf_[fv], af[fm], acc[fv][fm], 0, 0, 0);
  }

#pragma unroll
  for (int fv = 0; fv < 4; fv++) {
    int vb4 = v0 + fv * 16 + lg * 4;
    bool ok = (vb4 + 3) < VV;
    float4 bv = ok ? *(const float4*)(bias + vb4) : float4{0.f, 0.f, 0.f, 0.f};
#pragma unroll
    for (int fm = 0; fm < 4; fm++) {
      int m = m0 + fm * 16 + lr;
      if (ok) {
        float4 o;
        o.x = acc[fv][fm][0] + bv.x;
        o.y = acc[fv][fm][1] + bv.y;
        o.z = acc[fv][fm][2] + bv.z;
        o.w = acc[fv][fm][3] + bv.w;
        *(float4*)(y + (size_t)m * (size_t)VV + vb4) = o;
      }
    }
  }
}

extern "C" void kernel_launch(void* const* d_in, const int* in_sizes, int n_in,
                              void* d_out, int out_size, void* d_ws, size_t ws_size,
                              hipStream_t stream) {
  const float* x     = (const float*)d_in[0];
  const float* Wxs_w = (const float*)d_in[1];
  const float* Wxs_b = (const float*)d_in[2];
  const float* Wss_w = (const float*)d_in[3];
  const float* Wss_b = (const float*)d_in[4];
  const float* Wsy_w = (const float*)d_in[5];
  const float* Wsy_b = (const float*)d_in[6];
  float* y = (float*)d_out;
  char* ws = (char*)d_ws;

  u16*   xhi   = (u16*)(ws + OFF_XHI);
  u16*   xlo   = (u16*)(ws + OFF_XLO);
  u16*   whi   = (u16*)(ws + OFF_WHI);
  u16*   wlo   = (u16*)(ws + OFF_WLO);
  u16*   wsyb  = (u16*)(ws + OFF_WSY);
  float* xproj = (float*)(ws + OFF_XPROJ);
  u16*   hsb   = (u16*)(ws + OFF_HS);

  k0_convert<<<(NX + NW + NP) / 256, 256, 0, stream>>>(x, Wxs_w, Wsy_w, xhi, xlo, whi, wlo, wsyb);
  k1_xproj<<<128, 256, 0, stream>>>(xhi, xlo, whi, wlo, Wxs_b, xproj);
  k2_scan<<<16, 256, 0, stream>>>(xproj, Wss_w, Wss_b, hsb);
  k3_y<<<64 * 79, 256, 0, stream>>>(hsb, wsyb, Wsy_b, y);
}

// Round 7
// 280.964 us; speedup vs baseline: 2.0412x; 1.1231x over previous
//
#include <hip/hip_runtime.h>

typedef unsigned short u16;
typedef unsigned int u32;

using short8 = __attribute__((ext_vector_type(8))) short;
using f32x4  = __attribute__((ext_vector_type(4))) float;
using f32x2  = __attribute__((ext_vector_type(2))) float;

#define SSEQ 512
#define BB   16
#define DD   256
#define G4   256      // 4*SS
#define SSZ  64       // SS
#define VV   10000
#define VPAD 10112    // 79*128
#define MALL 8192     // BB*SSEQ

// ---- ws layout (bytes) ----
#define OFF_XHI   0u
#define OFF_XLO   4194304u
#define OFF_WHI   8388608u
#define OFF_WLO   8519680u
#define OFF_WSY   8650752u
#define OFF_XPROJ 9945088u
#define OFF_HS    18333696u

__device__ __forceinline__ u16 f2bf(float f) {
  u32 u = __float_as_uint(f);
  u32 r = (u + 0x7fffu + ((u >> 16) & 1u)) >> 16;
  return (u16)r;
}
__device__ __forceinline__ float bf2f(u16 h) {
  return __uint_as_float(((u32)h) << 16);
}
// packed dual-FMA: c += a*b elementwise
__device__ __forceinline__ f32x2 pkfma(f32x2 a, f32x2 b, f32x2 c) {
  asm("v_pk_fma_f32 %0, %1, %2, %0" : "+v"(c) : "v"(a), "v"(b));
  return c;
}
// quad butterfly add via DPP (VALU pipe)
// CTRL 0xB1 = quad_perm[1,0,3,2] (xor1), 0x4E = quad_perm[2,3,0,1] (xor2)
template <int CTRL>
__device__ __forceinline__ float qadd(float x) {
  int pv = __builtin_amdgcn_update_dpp(0, __float_as_int(x), CTRL, 0xf, 0xf, true);
  return x + __int_as_float(pv);
}
// quad broadcast of lane (CTRL lane id replicated): 0x00/0x55/0xAA/0xFF
template <int CTRL>
__device__ __forceinline__ float qbcast(float x) {
  int pv = __builtin_amdgcn_update_dpp(0, __float_as_int(x), CTRL, 0xf, 0xf, true);
  return __int_as_float(pv);
}

// ---------------- K0: fp32 -> bf16 (hi/lo split for x, Wxs; padded bf16 Wsy) ----
#define NX 2097152
#define NW 65536
#define NP 647168   // VPAD*64
__global__ void k0_convert(const float* __restrict__ x, const float* __restrict__ Wxs,
                           const float* __restrict__ Wsy,
                           u16* __restrict__ xhi, u16* __restrict__ xlo,
                           u16* __restrict__ whi, u16* __restrict__ wlo,
                           u16* __restrict__ wsyb) {
  int i = blockIdx.x * 256 + threadIdx.x;
  if (i < NX) {
    float v = x[i]; u16 h = f2bf(v);
    xhi[i] = h; xlo[i] = f2bf(v - bf2f(h));
  } else if (i < NX + NW) {
    int j = i - NX;
    float v = Wxs[j]; u16 h = f2bf(v);
    whi[j] = h; wlo[j] = f2bf(v - bf2f(h));
  } else if (i < NX + NW + NP) {
    int j = i - NX - NW;
    wsyb[j] = (j < VV * SSZ) ? f2bf(Wsy[j]) : (u16)0;
  }
}

// ---------------- K1: xproj = x @ Wxs^T + b   (double-bf16 MFMA, fp32 out) ------
__global__ __launch_bounds__(256) void k1_xproj(
    const u16* __restrict__ xhi, const u16* __restrict__ xlo,
    const u16* __restrict__ whi, const u16* __restrict__ wlo,
    const float* __restrict__ bias, float* __restrict__ xproj) {
  int bid = blockIdx.x;
  int mb = bid >> 1, nb = bid & 1;
  int tid = threadIdx.x, l = tid & 63, wid = tid >> 6;
  int wm = wid >> 1, wv = wid & 1;
  int m0 = mb * 128 + wm * 64, n0 = nb * 128 + wv * 64;
  int lr = l & 15, lg = l >> 4;

  f32x4 acc[4][4];
#pragma unroll
  for (int a = 0; a < 4; a++)
#pragma unroll
    for (int bq = 0; bq < 4; bq++) acc[a][bq] = (f32x4){0.f, 0.f, 0.f, 0.f};

#pragma unroll
  for (int p = 0; p < 3; p++) {
    const u16* A = (p == 1) ? xlo : xhi;
    const u16* B = (p == 2) ? wlo : whi;
#pragma unroll
    for (int ks = 0; ks < 8; ks++) {
      short8 af[4], bf_[4];
#pragma unroll
      for (int fm = 0; fm < 4; fm++)
        af[fm] = *(const short8*)(A + (size_t)(m0 + fm * 16 + lr) * 256 + ks * 32 + lg * 8);
#pragma unroll
      for (int fv = 0; fv < 4; fv++)
        bf_[fv] = *(const short8*)(B + (size_t)(n0 + fv * 16 + lr) * 256 + ks * 32 + lg * 8);
#pragma unroll
      for (int fm = 0; fm < 4; fm++)
#pragma unroll
        for (int fv = 0; fv < 4; fv++)
          acc[fm][fv] = __builtin_amdgcn_mfma_f32_16x16x32_bf16(af[fm], bf_[fv], acc[fm][fv], 0, 0, 0);
    }
  }
#pragma unroll
  for (int fv = 0; fv < 4; fv++) {
    int j = n0 + fv * 16 + lr;
    float bj = bias[j];
#pragma unroll
    for (int fm = 0; fm < 4; fm++)
#pragma unroll
      for (int r = 0; r < 4; r++) {
        int m = m0 + fm * 16 + lg * 4 + r;
        xproj[(size_t)m * 256 + j] = acc[fm][fv][r] + bj;
      }
  }
}

// ---------------- K2: serial LSTM scan. 16 blocks x 4 waves, k-split ----------
// Lane (w, oo=l>>2, ks=l&3): partial dot (k-slice [16ks,16ks+16)) for all 4
// gates of state jj=16w+oo; quad butterfly completes sums; lane activates ONLY
// gate ks (1 exp2+1 rcp) and loads ONLY gate ks's xproj (1 load/step, 4-deep
// register prefetch, unroll-4 for static slots); act broadcast via 4 mov_dpp.
// ONE lgkmcnt+barrier per step; no vmcnt drain in loop.
__global__ __launch_bounds__(256, 1) void k2_scan(
    const float* __restrict__ xproj, const float* __restrict__ Wss,
    const float* __restrict__ Wssb, u16* __restrict__ hsb) {
  __shared__ float hbuf[2][64];
  __shared__ u16 hstage[SSEQ][64];   // 64 KB

  int b = blockIdx.x, tid = threadIdx.x;
  int w = tid >> 6, l = tid & 63;
  int oo = l >> 2, ks = l & 3;
  int jj = w * 16 + oo;          // state this quad computes
  int ks16 = ks * 16;

  // weights: 4 gate-rows of state jj, k-slice [16ks,16ks+16) -> 64 VGPRs
  f32x2 wr[32];
#pragma unroll
  for (int g = 0; g < 4; g++) {
    const f32x2* pw = (const f32x2*)(Wss + (size_t)(g * 64 + jj) * 64 + ks16);
#pragma unroll
    for (int q = 0; q < 8; q++) wr[g * 8 + q] = pw[q];
  }
  float mybias = Wssb[ks * 64 + jj];   // this lane's gate row

  // activation constants for gate ks: sigm A=0,B=1,k=-1/ln2 ; tanh A=1,B=-2,k=2/ln2
  float kk = (ks == 2) ? 2.885390082f : -1.442695041f;
  float Ac = (ks == 2) ? 1.f : 0.f;
  float Bc = (ks == 2) ? -2.f : 1.f;

  // 4-deep xp prefetch (this lane's gate only)
  const float* xqp = xproj + (size_t)b * SSEQ * 256 + ks * 64 + jj;
  float xs0 = xqp[0 * 256];
  float xs1 = xqp[1 * 256];
  float xs2 = xqp[2 * 256];
  float xs3 = xqp[3 * 256];

  if (tid < 128) ((float*)hbuf)[tid] = 0.f;
  __syncthreads();

  float c = 0.f;   // state jj's cell, replicated across the quad

#define STEP(T, XS, RB, WB) { \
    f32x4 h4[4]; \
    const f32x4* hb = (const f32x4*)&hbuf[RB][ks16]; \
    h4[0] = hb[0]; h4[1] = hb[1]; h4[2] = hb[2]; h4[3] = hb[3]; \
    float p[4]; \
    _Pragma("unroll") \
    for (int g = 0; g < 4; g++) { \
      f32x2 a0 = (f32x2){0.f, 0.f}, a1 = (f32x2){0.f, 0.f}; \
      _Pragma("unroll") \
      for (int q = 0; q < 4; q++) { \
        f32x2 hA = (f32x2){h4[q][0], h4[q][1]}; \
        f32x2 hB = (f32x2){h4[q][2], h4[q][3]}; \
        a0 = pkfma(hA, wr[g * 8 + 2 * q], a0); \
        a1 = pkfma(hB, wr[g * 8 + 2 * q + 1], a1); \
      } \
      p[g] = (a0[0] + a0[1]) + (a1[0] + a1[1]); \
    } \
    _Pragma("unroll") \
    for (int g = 0; g < 4; g++) p[g] = qadd<0x4E>(qadd<0xB1>(p[g])); \
    float myp = (ks == 1) ? p[1] : p[0]; \
    myp = (ks == 2) ? p[2] : myp; \
    myp = (ks == 3) ? p[3] : myp; \
    float aa = myp + XS + mybias; \
    if ((T) + 4 < SSEQ) XS = xqp[(size_t)((T) + 4) * 256]; \
    float z = exp2f(kk * aa); \
    float act = fmaf(Bc, __builtin_amdgcn_rcpf(z + 1.f), Ac); \
    float fg = qbcast<0x00>(act); \
    float ig = qbcast<0x55>(act); \
    float gg = qbcast<0xAA>(act); \
    float og = qbcast<0xFF>(act); \
    c = fmaf(c, fg, ig * gg); \
    float hn = og * c;  /* faithful to reference: no tanh(c) */ \
    if (ks == 0) { \
      hbuf[WB][jj] = hn; \
      hstage[T][jj] = f2bf(hn); \
    } \
    asm volatile("s_waitcnt lgkmcnt(0)\n\ts_barrier" ::: "memory"); \
  }

  for (int t = 0; t < SSEQ; t += 4) {
    STEP(t + 0, xs0, 1, 0)
    STEP(t + 1, xs1, 0, 1)
    STEP(t + 2, xs2, 1, 0)
    STEP(t + 3, xs3, 0, 1)
  }
#undef STEP

  // coalesced dump of staged h history (64 KB) to global
  __syncthreads();
  const uint4* src = (const uint4*)hstage;
  uint4* dst = (uint4*)(hsb + (size_t)b * SSEQ * 64);
#pragma unroll
  for (int i = 0; i < 16; i++) dst[tid + 256 * i] = src[tid + 256 * i];
}

// ---------------- K3: y = hs @ Wsy^T + b   (bf16 MFMA, swapped operands) -------
__global__ __launch_bounds__(256) void k3_y(
    const u16* __restrict__ hsb, const u16* __restrict__ wsyb,
    const float* __restrict__ bias, float* __restrict__ y) {
  int bid = blockIdx.x;
  int mb = bid / 79, vb = bid - mb * 79;
  int tid = threadIdx.x, l = tid & 63, wid = tid >> 6;
  int wm = wid >> 1, wv = wid & 1;
  int m0 = mb * 128 + wm * 64, v0 = vb * 128 + wv * 64;
  int lr = l & 15, lg = l >> 4;

  f32x4 acc[4][4];  // [fv][fm]
#pragma unroll
  for (int a = 0; a < 4; a++)
#pragma unroll
    for (int bq = 0; bq < 4; bq++) acc[a][bq] = (f32x4){0.f, 0.f, 0.f, 0.f};

#pragma unroll
  for (int ks = 0; ks < 2; ks++) {
    short8 af[4], bf_[4];
#pragma unroll
    for (int fm = 0; fm < 4; fm++)
      af[fm] = *(const short8*)(hsb + (size_t)(m0 + fm * 16 + lr) * 64 + ks * 32 + lg * 8);
#pragma unroll
    for (int fv = 0; fv < 4; fv++)
      bf_[fv] = *(const short8*)(wsyb + (size_t)(v0 + fv * 16 + lr) * 64 + ks * 32 + lg * 8);
#pragma unroll
    for (int fv = 0; fv < 4; fv++)
#pragma unroll
      for (int fm = 0; fm < 4; fm++)
        acc[fv][fm] = __builtin_amdgcn_mfma_f32_16x16x32_bf16(bf_[fv], af[fm], acc[fv][fm], 0, 0, 0);
  }

#pragma unroll
  for (int fv = 0; fv < 4; fv++) {
    int vb4 = v0 + fv * 16 + lg * 4;
    bool ok = (vb4 + 3) < VV;
    float4 bv = ok ? *(const float4*)(bias + vb4) : float4{0.f, 0.f, 0.f, 0.f};
#pragma unroll
    for (int fm = 0; fm < 4; fm++) {
      int m = m0 + fm * 16 + lr;
      if (ok) {
        float4 o;
        o.x = acc[fv][fm][0] + bv.x;
        o.y = acc[fv][fm][1] + bv.y;
        o.z = acc[fv][fm][2] + bv.z;
        o.w = acc[fv][fm][3] + bv.w;
        *(float4*)(y + (size_t)m * (size_t)VV + vb4) = o;
      }
    }
  }
}

extern "C" void kernel_launch(void* const* d_in, const int* in_sizes, int n_in,
                              void* d_out, int out_size, void* d_ws, size_t ws_size,
                              hipStream_t stream) {
  const float* x     = (const float*)d_in[0];
  const float* Wxs_w = (const float*)d_in[1];
  const float* Wxs_b = (const float*)d_in[2];
  const float* Wss_w = (const float*)d_in[3];
  const float* Wss_b = (const float*)d_in[4];
  const float* Wsy_w = (const float*)d_in[5];
  const float* Wsy_b = (const float*)d_in[6];
  float* y = (float*)d_out;
  char* ws = (char*)d_ws;

  u16*   xhi   = (u16*)(ws + OFF_XHI);
  u16*   xlo   = (u16*)(ws + OFF_XLO);
  u16*   whi   = (u16*)(ws + OFF_WHI);
  u16*   wlo   = (u16*)(ws + OFF_WLO);
  u16*   wsyb  = (u16*)(ws + OFF_WSY);
  float* xproj = (float*)(ws + OFF_XPROJ);
  u16*   hsb   = (u16*)(ws + OFF_HS);

  k0_convert<<<(NX + NW + NP) / 256, 256, 0, stream>>>(x, Wxs_w, Wsy_w, xhi, xlo, whi, wlo, wsyb);
  k1_xproj<<<128, 256, 0, stream>>>(xhi, xlo, whi, wlo, Wxs_b, xproj);
  k2_scan<<<16, 256, 0, stream>>>(xproj, Wss_w, Wss_b, hsb);
  k3_y<<<64 * 79, 256, 0, stream>>>(hsb, wsyb, Wsy_b, y);
}